// Round 7
// baseline (346.910 us; speedup 1.0000x reference)
//
#include <hip/hip_runtime.h>

// Fused ShiftedWindowMSA, round 11 (resubmit — R6 bench was an infra
// GPUAcquisitionTimeout, no measurement): Q and o in REGISTERS; q_s deleted.
// Insight: D[n'][p] puts position=lane-column, so a wave computing Q channels
// for ITS OWN 16 rows (B-operand = x-frag of its own m) keeps Q wave-local.
// The Q->bq and o->bo relayouts are the SAME 4-lane-group permutation as the
// existing P relayout (src lane = lrow + 32*(lq&1) (+16), tile 2h+(lq>>1),
// dword w&1). LDS drops 31152 -> 20960 B -> 7 blocks LDS-wise; bounds (256,6).
// GEMM1 rebalanced: each wave computes 6 Q-tiles (own positions) + 3 K/V
// N-tiles x 4 position-tiles (LDS) = 18 tiles uniform (was 20, uneven).
// Everything else is byte-identical R5 (strides 104/56, no setprio, no-max
// softmax, sum off critical path, same head pipeline, same GEMM2 tail).
//
// LDS map (bytes):
//  k  @0      49x104 f16 (10192)  K row-major
//  vt @10192  96x56 (10752)+16B zeroed pad   V^T [chan][pos], pos 49..55 zero
// total 20960 -> 7 blocks/CU by LDS; 6 by (256,6) VGPR cap.
// Garbage-safety: all cross-lane shuffles (P, bq, bo, sum) stay within the
// 4-lane group sharing lrow = same m -> garbage confined to m>=49 columns,
// dropped by the final out-store guard. k over-reads (rows 49..63) land in
// vt region (finite); vt frag1 overrun ends exactly at the zeroed 16B tail
// (max elem 95*56+63 = 5383 < 5384) and multiplies P(n>=49)=0. Masked cols:
// fmaf -> -3e38 -> __expf -> +0 exactly.

typedef _Float16 f16;
typedef _Float16 f16x2 __attribute__((ext_vector_type(2)));
typedef _Float16 f16x4 __attribute__((ext_vector_type(4)));
typedef _Float16 f16x8 __attribute__((ext_vector_type(8)));
typedef float f32x4 __attribute__((ext_vector_type(4)));

static __device__ __forceinline__ f32x4 mfma16(f16x8 a, f16x8 b, f32x4 c) {
    return __builtin_amdgcn_mfma_f32_16x16x32_f16(a, b, c, 0, 0, 0);
}
static __device__ __forceinline__ f16x8 cvt8(const float* __restrict__ p) {
    float4 f0 = *(const float4*)(p);
    float4 f1 = *(const float4*)(p + 4);
    f16x8 h;
    h[0]=(f16)f0.x; h[1]=(f16)f0.y; h[2]=(f16)f0.z; h[3]=(f16)f0.w;
    h[4]=(f16)f1.x; h[5]=(f16)f1.y; h[6]=(f16)f1.z; h[7]=(f16)f1.w;
    return h;
}
static __device__ __forceinline__ f16x8 cvt8p(const float4& f0, const float4& f1) {
    f16x8 h;
    h[0]=(f16)f0.x; h[1]=(f16)f0.y; h[2]=(f16)f0.z; h[3]=(f16)f0.w;
    h[4]=(f16)f1.x; h[5]=(f16)f1.y; h[6]=(f16)f1.z; h[7]=(f16)f1.w;
    return h;
}

#define QK_STR 104
#define VT_STR 56
#define SMEM_BYTES 20960
#define OFF_VT 10192

union U2 { int i; f16x2 h; };
union U8 { int i[4]; f16x8 h; };

template<bool WS>
__global__ __launch_bounds__(256, 6) void swin_fused(
    const float* __restrict__ x, const float* __restrict__ w1,
    const float* __restrict__ b1, const float* __restrict__ w2,
    const float* __restrict__ b2, float* __restrict__ out,
    const f16* __restrict__ w1p, const f16* __restrict__ w2p,
    const float* __restrict__ b1p)
{
    __shared__ __align__(16) char smem[SMEM_BYTES];
    f16* k_s  = (f16*)(smem);
    f16* vt_s = (f16*)(smem + OFF_VT);

    const int tid  = threadIdx.x;
    const int wv   = tid >> 6;
    const int lane = tid & 63;
    const int lrow = lane & 15;
    const int lq   = lane >> 4;
    const int m    = wv * 16 + lrow;            // this lane's query row

    const int bx = blockIdx.x;
    const int b  = bx >> 6;
    const int wz = bx & 63;
    const int wh = wz >> 3;
    const int ww = wz & 7;

    const float* xb = x + b * (3136 * 96);

    // zero vt pos-pad (49..55) + 16B tail pad (disjoint from GEMM1 stores)
    if (tid < 96) {
        #pragma unroll
        for (int p7 = 49; p7 < 56; ++p7) vt_s[tid * VT_STR + p7] = (f16)0.f;
    }
    if (tid < 8) vt_s[96 * VT_STR + tid] = (f16)0.f;

    // 4-lane-group relayout indices (shared by P, bq, bo relayouts)
    const int idxA = lrow + 32 * (lq & 1);
    const int idxB = idxA + 16;

    f16x8 bq[3];

    // ---- GEMM1: Q wave-local in regs; K/V via LDS ----
    {
        // x row for this lane's own position (Q B-operand), clamped dup >=49
        int pcq = (m < 49) ? m : 48;
        int iq = pcq / 7, jq = pcq - iq * 7;
        int rq = wh * 7 + iq + 4; if (rq >= 56) rq -= 56;
        int cq = ww * 7 + jq + 4; if (cq >= 56) cq -= 56;
        const float* xqr = xb + (rq * 56 + cq) * 96;
        float4 xq[3][2];
        #pragma unroll
        for (int ks = 0; ks < 3; ++ks) {
            xq[ks][0] = *(const float4*)(xqr + ks * 32 + lq * 8);
            xq[ks][1] = *(const float4*)(xqr + ks * 32 + lq * 8 + 4);
        }

        // per-pt x row pointers (shift/roll mapping) + first pt buffer issue
        const float* xrow[4];
        #pragma unroll
        for (int pt = 0; pt < 4; ++pt) {
            int p  = pt * 16 + lrow;
            int pc = (p < 49) ? p : 48;
            int i  = pc / 7, j = pc - i * 7;
            int r  = wh * 7 + i + 4; if (r >= 56) r -= 56;
            int c  = ww * 7 + j + 4; if (c >= 56) c -= 56;
            xrow[pt] = xb + (r * 56 + c) * 96;
        }
        float4 xbuf0[3][2], xbuf1[3][2];
        #pragma unroll
        for (int ks = 0; ks < 3; ++ks) {
            xbuf0[ks][0] = *(const float4*)(xrow[0] + ks * 32 + lq * 8);
            xbuf0[ks][1] = *(const float4*)(xrow[0] + ks * 32 + lq * 8 + 4);
        }

        // K/V weight tiles: 3 per wave, ot = 6 + wv + 4t
        f16x8 bf[3][3]; int kqv[3], cb[3], ob[3];
        #pragma unroll
        for (int t = 0; t < 3; ++t) {
            int ot = 6 + wv + 4 * t;
            int kv = ot / 6;                   // 1 = K, 2 = V
            kqv[t] = kv; cb[t] = (ot - kv * 6) * 16; ob[t] = ot * 16;
            if constexpr (WS) {
                #pragma unroll
                for (int ks = 0; ks < 3; ++ks)
                    bf[t][ks] = *(const f16x8*)(w1p + (ot*16 + lrow)*96 + ks*32 + lq*8);
            } else {
                int srowA = (ot*16 + lrow - kv*96) * 3 + kv;
                #pragma unroll
                for (int ks = 0; ks < 3; ++ks)
                    bf[t][ks] = cvt8(w1 + srowA*96 + ks*32 + lq*8);
            }
        }

        // Q tiles: all 6, B-operand = own-position x fragment
        f16x8 xfq[3];
        #pragma unroll
        for (int ks = 0; ks < 3; ++ks) xfq[ks] = cvt8p(xq[ks][0], xq[ks][1]);
        int qdlo[6], qdhi[6];
        #pragma unroll
        for (int ot = 0; ot < 6; ++ot) {
            f16x8 aq[3];
            if constexpr (WS) {
                #pragma unroll
                for (int ks = 0; ks < 3; ++ks)
                    aq[ks] = *(const f16x8*)(w1p + (ot*16 + lrow)*96 + ks*32 + lq*8);
            } else {
                int srowA = (ot*16 + lrow) * 3;
                #pragma unroll
                for (int ks = 0; ks < 3; ++ks)
                    aq[ks] = cvt8(w1 + srowA*96 + ks*32 + lq*8);
            }
            f32x4 acc = {0.f, 0.f, 0.f, 0.f};
            #pragma unroll
            for (int ks = 0; ks < 3; ++ks) acc = mfma16(aq[ks], xfq[ks], acc);
            f32x4 br;
            if constexpr (WS) {
                br = *(const f32x4*)(b1p + ot*16 + lq*4);
            } else {
                #pragma unroll
                for (int i2 = 0; i2 < 4; ++i2)
                    br[i2] = b1[(ot*16 + lq*4 + i2) * 3];
            }
            U2 lo, hi;
            lo.h[0] = (f16)(acc[0] + br[0]); lo.h[1] = (f16)(acc[1] + br[1]);
            hi.h[0] = (f16)(acc[2] + br[2]); hi.h[1] = (f16)(acc[3] + br[3]);
            qdlo[ot] = lo.i; qdhi[ot] = hi.i;
        }
        // qd -> bq (same 4-lane-group permutation as P relayout)
        #pragma unroll
        for (int hh = 0; hh < 3; ++hh) {
            U8 u;
            #pragma unroll
            for (int w = 0; w < 4; ++w) {
                int idx = (w < 2) ? idxA : idxB;
                int v0 = __shfl((w & 1) ? qdhi[2*hh]     : qdlo[2*hh],     idx);
                int v1 = __shfl((w & 1) ? qdhi[2*hh + 1] : qdlo[2*hh + 1], idx);
                u.i[w] = (lq & 2) ? v1 : v0;
            }
            bq[hh] = u.h;
        }

        // K/V: pt-loop, x double-buffered
        #pragma unroll
        for (int pt = 0; pt < 4; ++pt) {
            float4 (*cur)[2] = (pt & 1) ? xbuf1 : xbuf0;
            float4 (*nxt)[2] = (pt & 1) ? xbuf0 : xbuf1;
            if (pt < 3) {
                #pragma unroll
                for (int ks = 0; ks < 3; ++ks) {
                    nxt[ks][0] = *(const float4*)(xrow[pt+1] + ks * 32 + lq * 8);
                    nxt[ks][1] = *(const float4*)(xrow[pt+1] + ks * 32 + lq * 8 + 4);
                }
            }
            f16x8 xf[3];
            #pragma unroll
            for (int ks = 0; ks < 3; ++ks) xf[ks] = cvt8p(cur[ks][0], cur[ks][1]);
            const int  p   = pt * 16 + lrow;
            const bool pok = (p < 49);
            #pragma unroll
            for (int t = 0; t < 3; ++t) {
                f32x4 acc = {0.f, 0.f, 0.f, 0.f};
                if (kqv[t] == 2) {
                    // V: D[p][c]; lane = channel cc, rows p4..p4+3
                    #pragma unroll
                    for (int ks = 0; ks < 3; ++ks) acc = mfma16(xf[ks], bf[t][ks], acc);
                    float bc;
                    if constexpr (WS) bc = b1p[ob[t] + lrow];
                    else              bc = b1[(ob[t] + lrow - 192)*3 + 2];
                    int cc = cb[t] + lrow;
                    f16x4 pk;
                    #pragma unroll
                    for (int i2 = 0; i2 < 4; ++i2) pk[i2] = (f16)(acc[i2] + bc);
                    int p4 = pt * 16 + lq * 4;
                    if (p4 < 45)       *(f16x4*)(vt_s + cc * VT_STR + p4) = pk;
                    else if (p4 == 48) vt_s[cc * VT_STR + 48] = pk[0];
                } else {
                    // K: D[n'][p]; lane = position p, rows = 4 channels
                    #pragma unroll
                    for (int ks = 0; ks < 3; ++ks) acc = mfma16(bf[t][ks], xf[ks], acc);
                    if (pok) {
                        f32x4 br;
                        if constexpr (WS) {
                            br = *(const f32x4*)(b1p + ob[t] + lq*4);
                        } else {
                            #pragma unroll
                            for (int i2 = 0; i2 < 4; ++i2)
                                br[i2] = b1[(ob[t] + lq*4 + i2 - 96)*3 + 1];
                        }
                        f16x4 pk;
                        #pragma unroll
                        for (int i2 = 0; i2 < 4; ++i2) pk[i2] = (f16)(acc[i2] + br[i2]);
                        *(f16x4*)(k_s + p * QK_STR + cb[t] + lq * 4) = pk;
                    }
                }
            }
        }
    }
    __syncthreads();   // THE barrier: publish k/vt (+pads) to all waves

    const bool mrow = (wh == 7), mcol = (ww == 7);
    const float scale = 0.17677669529663687f;   // 1/sqrt(32)

    // mask values, head-invariant: 0 or -3e38 added via fmaf
    float mv[16];
    {
        const bool am = (m >= 28);
        const bool a4 = (m % 7) >= 4;
        #pragma unroll
        for (int nt = 0; nt < 4; ++nt)
            #pragma unroll
            for (int i2 = 0; i2 < 4; ++i2) {
                int nn = nt * 16 + lq * 4 + i2;
                bool ok = (nn < 49)
                       && (!mrow || (am == (nn >= 28)))
                       && (!mcol || (a4 == ((nn % 7) >= 4)));
                mv[nt*4 + i2] = ok ? 0.f : -3e38f;
            }
    }

    int odlo[6], odhi[6];   // o tiles in registers (consumed by GEMM2)

    // head-pipelined attention: sc holds head hh's S^T; QK(hh+1) runs after
    // PV(hh), its ak loads are issued before softmax(hh).
    f32x4 sc[4];
    #pragma unroll
    for (int nt = 0; nt < 4; ++nt) {
        f16x8 ak = *(const f16x8*)(k_s + (nt*16 + lrow)*QK_STR + lq*8);
        f32x4 z = {0.f, 0.f, 0.f, 0.f};
        sc[nt] = mfma16(ak, bq[0], z);
    }

    #pragma unroll
    for (int hh = 0; hh < 3; ++hh) {
        // issue next head's K-fragment loads (latency hides under softmax)
        f16x8 akn[4];
        if (hh < 2) {
            #pragma unroll
            for (int nt = 0; nt < 4; ++nt)
                akn[nt] = *(const f16x8*)(k_s + (nt*16 + lrow)*QK_STR + (hh+1)*32 + lq*8);
        }
        // V^T loads for this head's PV (also hidden under softmax)
        f16x8 va[2][2];
        #pragma unroll
        for (int et = 0; et < 2; ++et) {
            int vrow = hh * 32 + et * 16 + lrow;
            va[et][0] = *(const f16x8*)(vt_s + vrow * VT_STR + lq * 8);
            va[et][1] = *(const f16x8*)(vt_s + vrow * VT_STR + 32 + lq * 8);
        }
        // no-max softmax: ev = exp(scale*S + mask); masked -> exp(-3e38) = +0.
        float ev[16];
        #pragma unroll
        for (int nt = 0; nt < 4; ++nt)
            #pragma unroll
            for (int i2 = 0; i2 < 4; ++i2)
                ev[nt*4 + i2] = __expf(fmaf(sc[nt][i2], scale, mv[nt*4 + i2]));
        // in-lane partial sum; cross-lane combine deferred past the relayout
        float ts[8];
        #pragma unroll
        for (int k2 = 0; k2 < 8; ++k2) ts[k2] = ev[2*k2] + ev[2*k2+1];
        #pragma unroll
        for (int k2 = 0; k2 < 4; ++k2) ts[k2] += ts[k2+4];
        float sp = (ts[0] + ts[1]) + (ts[2] + ts[3]);

        // pack unnormalized P into dwords: pd[nt][d]
        int pd[4][2];
        #pragma unroll
        for (int nt = 0; nt < 4; ++nt) {
            U2 u0, u1;
            u0.h[0] = (f16)ev[nt*4+0]; u0.h[1] = (f16)ev[nt*4+1];
            u1.h[0] = (f16)ev[nt*4+2]; u1.h[1] = (f16)ev[nt*4+3];
            pd[nt][0] = u0.i; pd[nt][1] = u1.i;
        }
        // relayout S^T regs -> PV B-frags among the 4 lanes sharing m
        U8 ub0, ub1;
        #pragma unroll
        for (int w = 0; w < 4; ++w) {
            int idx = (w < 2) ? idxA : idxB;
            int rr  = w & 1;
            int a0v = __shfl(pd[0][rr], idx);
            int a1v = __shfl(pd[1][rr], idx);
            ub0.i[w] = (lq & 2) ? a1v : a0v;
            int c0v = __shfl(pd[2][rr], idx);
            int c1v = __shfl(pd[3][rr], idx);
            ub1.i[w] = (lq & 2) ? c1v : c0v;
        }
        // sum combine runs concurrently with relayout + PV
        float ssum = sp;
        ssum += __shfl_xor(ssum, 16);
        ssum += __shfl_xor(ssum, 32);
        float inv = 1.0f / ssum;

        // PV swapped: D[e][m]; pack straight to o register tiles
        #pragma unroll
        for (int et = 0; et < 2; ++et) {
            f32x4 z = {0.f, 0.f, 0.f, 0.f};
            f32x4 oc = mfma16(va[et][0], ub0.h, z);
            oc = mfma16(va[et][1], ub1.h, oc);
            U2 lo, hi;
            lo.h[0] = (f16)(oc[0] * inv); lo.h[1] = (f16)(oc[1] * inv);
            hi.h[0] = (f16)(oc[2] * inv); hi.h[1] = (f16)(oc[3] * inv);
            odlo[2*hh + et] = lo.i; odhi[2*hh + et] = hi.i;
        }
        // next head's QK (akn long since arrived)
        if (hh < 2) {
            #pragma unroll
            for (int nt = 0; nt < 4; ++nt) {
                f32x4 z = {0.f, 0.f, 0.f, 0.f};
                sc[nt] = mfma16(akn[nt], bq[hh+1], z);
            }
        }
    }

    // ---- GEMM2 (swapped, 2-stage w2p prefetch): bo from od via shuffles ----
    {
        f16x8 bo[3];
        #pragma unroll
        for (int ks = 0; ks < 3; ++ks) {
            U8 u;
            #pragma unroll
            for (int w = 0; w < 4; ++w) {
                int idx = (w < 2) ? idxA : idxB;
                int v0 = __shfl((w & 1) ? odhi[2*ks]     : odlo[2*ks],     idx);
                int v1 = __shfl((w & 1) ? odhi[2*ks + 1] : odlo[2*ks + 1], idx);
                u.i[w] = (lq & 2) ? v1 : v0;
            }
            bo[ks] = u.h;
        }
        int mm2 = (m < 49) ? m : 48;
        int i = mm2 / 7, j = mm2 - i * 7;
        int orow = wh * 7 + i + 3; if (orow >= 56) orow -= 56;
        int ocol = ww * 7 + j + 3; if (ocol >= 56) ocol -= 56;
        float* op = out + (size_t)(b * 3136 + orow * 56 + ocol) * 96;

        f16x8 aw0[3], aw1[3];
        #pragma unroll
        for (int ks = 0; ks < 3; ++ks) {
            if constexpr (WS)
                aw0[ks] = *(const f16x8*)(w2p + lrow*96 + ks*32 + lq*8);
            else
                aw0[ks] = cvt8(w2 + lrow*96 + ks*32 + lq*8);
        }
        #pragma unroll
        for (int ot2 = 0; ot2 < 6; ++ot2) {
            f16x8* cw = (ot2 & 1) ? aw1 : aw0;
            f16x8* nw = (ot2 & 1) ? aw0 : aw1;
            if (ot2 < 5) {
                #pragma unroll
                for (int ks = 0; ks < 3; ++ks) {
                    if constexpr (WS)
                        nw[ks] = *(const f16x8*)(w2p + ((ot2+1)*16 + lrow)*96 + ks*32 + lq*8);
                    else
                        nw[ks] = cvt8(w2 + ((ot2+1)*16 + lrow)*96 + ks*32 + lq*8);
                }
            }
            f32x4 acc = {0.f, 0.f, 0.f, 0.f};
            #pragma unroll
            for (int ks = 0; ks < 3; ++ks) acc = mfma16(cw[ks], bo[ks], acc);
            f32x4 bias = *(const f32x4*)(b2 + ot2 * 16 + lq * 4);
            if (m < 49) {
                f32x4 o4 = acc + bias;
                *(f32x4*)(op + ot2 * 16 + lq * 4) = o4;
            }
        }
    }
}

// Pre-permute + f16-convert weights into d_ws (runs every launch; graph-safe).
__global__ void prep_weights(const float* __restrict__ w1, const float* __restrict__ b1,
                             const float* __restrict__ w2,
                             f16* __restrict__ w1p, f16* __restrict__ w2p,
                             float* __restrict__ b1p)
{
    int idx = blockIdx.x * 256 + threadIdx.x;
    if (idx < 27648) {                 // w1p[n'][k], n' = kq*96 + c96
        int np = idx / 96, k = idx - np * 96;
        int kq = np / 96, c96 = np - kq * 96;
        w1p[idx] = (f16)w1[(c96 * 3 + kq) * 96 + k];
    } else if (idx < 36864) {
        int i2 = idx - 27648;
        w2p[i2] = (f16)w2[i2];
    } else if (idx < 37152) {
        int np = idx - 36864;
        int kq = np / 96, c96 = np - kq * 96;
        b1p[np] = b1[c96 * 3 + kq];
    }
}

extern "C" void kernel_launch(void* const* d_in, const int* in_sizes, int n_in,
                              void* d_out, int out_size, void* d_ws, size_t ws_size,
                              hipStream_t stream) {
    const float* x  = (const float*)d_in[0];
    const float* w1 = (const float*)d_in[1];
    const float* b1 = (const float*)d_in[2];
    const float* w2 = (const float*)d_in[3];
    const float* b2 = (const float*)d_in[4];
    float* out = (float*)d_out;

    const size_t need = 27648u * 2 + 9216u * 2 + 288u * 4;   // 74,880 B
    if (ws_size >= need) {
        f16*   w1p = (f16*)d_ws;
        f16*   w2p = w1p + 27648;
        float* b1p = (float*)(w2p + 9216);
        prep_weights<<<dim3(146), dim3(256), 0, stream>>>(w1, b1, w2, w1p, w2p, b1p);
        swin_fused<true><<<dim3(4096), dim3(256), 0, stream>>>(
            x, w1, b1, w2, b2, out, w1p, w2p, b1p);
    } else {
        swin_fused<false><<<dim3(4096), dim3(256), 0, stream>>>(
            x, w1, b1, w2, b2, out, nullptr, nullptr, nullptr);
    }
}

// Round 8
// 247.129 us; speedup vs baseline: 1.4038x; 1.4038x over previous
//
#include <hip/hip_runtime.h>

// Fused ShiftedWindowMSA, round 12: R11 structure (Q and o in registers,
// q_s deleted) with the launch bound reverted to the known-good (256,4).
// R7 post-mortem: (256,6) forced the allocator to spill (~400MB scratch
// traffic/dispatch: FETCH 310MB, WRITE 322MB, VGPR=40) — occupancy hit 60%
// but every gain drowned in scratch. (256,4) = VGPR cap 128, no spill; the
// compiler historically lands exactly on the 64-VGPR occupancy cliff at this
// state size (R2-R5 all compiled to 64). If it lands <=64 again: LDS 20992
// -> 7 blocks/CU x 4 waves = 28 waves/CU (87%) vs R5's measured 13.4 ->
// direct test of the latency-hiding theory with an unchanged inner stream.
//
// LDS map (bytes):
//  k  @0      49x104 f16 (10192)  K row-major
//  vt @10192  96x56 (10752)+16B zeroed pad   V^T [chan][pos], pos 49..55 zero
// total 20960.
// Garbage-safety: all cross-lane shuffles (P, bq, bo, sum) stay within the
// 4-lane group sharing lrow = same m -> garbage confined to m>=49 columns,
// dropped by the final out-store guard. k over-reads (rows 49..63) land in
// vt region (finite); vt frag1 overrun ends exactly at the zeroed 16B tail
// (max elem 95*56+63 = 5383 < 5384) and multiplies P(n>=49)=0. Masked cols:
// fmaf -> -3e38 -> __expf -> +0 exactly.

typedef _Float16 f16;
typedef _Float16 f16x2 __attribute__((ext_vector_type(2)));
typedef _Float16 f16x4 __attribute__((ext_vector_type(4)));
typedef _Float16 f16x8 __attribute__((ext_vector_type(8)));
typedef float f32x4 __attribute__((ext_vector_type(4)));

static __device__ __forceinline__ f32x4 mfma16(f16x8 a, f16x8 b, f32x4 c) {
    return __builtin_amdgcn_mfma_f32_16x16x32_f16(a, b, c, 0, 0, 0);
}
static __device__ __forceinline__ f16x8 cvt8(const float* __restrict__ p) {
    float4 f0 = *(const float4*)(p);
    float4 f1 = *(const float4*)(p + 4);
    f16x8 h;
    h[0]=(f16)f0.x; h[1]=(f16)f0.y; h[2]=(f16)f0.z; h[3]=(f16)f0.w;
    h[4]=(f16)f1.x; h[5]=(f16)f1.y; h[6]=(f16)f1.z; h[7]=(f16)f1.w;
    return h;
}
static __device__ __forceinline__ f16x8 cvt8p(const float4& f0, const float4& f1) {
    f16x8 h;
    h[0]=(f16)f0.x; h[1]=(f16)f0.y; h[2]=(f16)f0.z; h[3]=(f16)f0.w;
    h[4]=(f16)f1.x; h[5]=(f16)f1.y; h[6]=(f16)f1.z; h[7]=(f16)f1.w;
    return h;
}

#define QK_STR 104
#define VT_STR 56
#define SMEM_BYTES 20960
#define OFF_VT 10192

union U2 { int i; f16x2 h; };
union U8 { int i[4]; f16x8 h; };

template<bool WS>
__global__ __launch_bounds__(256, 4) void swin_fused(
    const float* __restrict__ x, const float* __restrict__ w1,
    const float* __restrict__ b1, const float* __restrict__ w2,
    const float* __restrict__ b2, float* __restrict__ out,
    const f16* __restrict__ w1p, const f16* __restrict__ w2p,
    const float* __restrict__ b1p)
{
    __shared__ __align__(16) char smem[SMEM_BYTES];
    f16* k_s  = (f16*)(smem);
    f16* vt_s = (f16*)(smem + OFF_VT);

    const int tid  = threadIdx.x;
    const int wv   = tid >> 6;
    const int lane = tid & 63;
    const int lrow = lane & 15;
    const int lq   = lane >> 4;
    const int m    = wv * 16 + lrow;            // this lane's query row

    const int bx = blockIdx.x;
    const int b  = bx >> 6;
    const int wz = bx & 63;
    const int wh = wz >> 3;
    const int ww = wz & 7;

    const float* xb = x + b * (3136 * 96);

    // zero vt pos-pad (49..55) + 16B tail pad (disjoint from GEMM1 stores)
    if (tid < 96) {
        #pragma unroll
        for (int p7 = 49; p7 < 56; ++p7) vt_s[tid * VT_STR + p7] = (f16)0.f;
    }
    if (tid < 8) vt_s[96 * VT_STR + tid] = (f16)0.f;

    // 4-lane-group relayout indices (shared by P, bq, bo relayouts)
    const int idxA = lrow + 32 * (lq & 1);
    const int idxB = idxA + 16;

    f16x8 bq[3];

    // ---- GEMM1: Q wave-local in regs; K/V via LDS ----
    {
        // x row for this lane's own position (Q B-operand), clamped dup >=49
        int pcq = (m < 49) ? m : 48;
        int iq = pcq / 7, jq = pcq - iq * 7;
        int rq = wh * 7 + iq + 4; if (rq >= 56) rq -= 56;
        int cq = ww * 7 + jq + 4; if (cq >= 56) cq -= 56;
        const float* xqr = xb + (rq * 56 + cq) * 96;
        float4 xq[3][2];
        #pragma unroll
        for (int ks = 0; ks < 3; ++ks) {
            xq[ks][0] = *(const float4*)(xqr + ks * 32 + lq * 8);
            xq[ks][1] = *(const float4*)(xqr + ks * 32 + lq * 8 + 4);
        }

        // per-pt x row pointers (shift/roll mapping) + first pt buffer issue
        const float* xrow[4];
        #pragma unroll
        for (int pt = 0; pt < 4; ++pt) {
            int p  = pt * 16 + lrow;
            int pc = (p < 49) ? p : 48;
            int i  = pc / 7, j = pc - i * 7;
            int r  = wh * 7 + i + 4; if (r >= 56) r -= 56;
            int c  = ww * 7 + j + 4; if (c >= 56) c -= 56;
            xrow[pt] = xb + (r * 56 + c) * 96;
        }
        float4 xbuf0[3][2], xbuf1[3][2];
        #pragma unroll
        for (int ks = 0; ks < 3; ++ks) {
            xbuf0[ks][0] = *(const float4*)(xrow[0] + ks * 32 + lq * 8);
            xbuf0[ks][1] = *(const float4*)(xrow[0] + ks * 32 + lq * 8 + 4);
        }

        // K/V weight tiles: 3 per wave, ot = 6 + wv + 4t
        f16x8 bf[3][3]; int kqv[3], cb[3], ob[3];
        #pragma unroll
        for (int t = 0; t < 3; ++t) {
            int ot = 6 + wv + 4 * t;
            int kv = ot / 6;                   // 1 = K, 2 = V
            kqv[t] = kv; cb[t] = (ot - kv * 6) * 16; ob[t] = ot * 16;
            if constexpr (WS) {
                #pragma unroll
                for (int ks = 0; ks < 3; ++ks)
                    bf[t][ks] = *(const f16x8*)(w1p + (ot*16 + lrow)*96 + ks*32 + lq*8);
            } else {
                int srowA = (ot*16 + lrow - kv*96) * 3 + kv;
                #pragma unroll
                for (int ks = 0; ks < 3; ++ks)
                    bf[t][ks] = cvt8(w1 + srowA*96 + ks*32 + lq*8);
            }
        }

        // Q tiles: all 6, B-operand = own-position x fragment
        f16x8 xfq[3];
        #pragma unroll
        for (int ks = 0; ks < 3; ++ks) xfq[ks] = cvt8p(xq[ks][0], xq[ks][1]);
        int qdlo[6], qdhi[6];
        #pragma unroll
        for (int ot = 0; ot < 6; ++ot) {
            f16x8 aq[3];
            if constexpr (WS) {
                #pragma unroll
                for (int ks = 0; ks < 3; ++ks)
                    aq[ks] = *(const f16x8*)(w1p + (ot*16 + lrow)*96 + ks*32 + lq*8);
            } else {
                int srowA = (ot*16 + lrow) * 3;
                #pragma unroll
                for (int ks = 0; ks < 3; ++ks)
                    aq[ks] = cvt8(w1 + srowA*96 + ks*32 + lq*8);
            }
            f32x4 acc = {0.f, 0.f, 0.f, 0.f};
            #pragma unroll
            for (int ks = 0; ks < 3; ++ks) acc = mfma16(aq[ks], xfq[ks], acc);
            f32x4 br;
            if constexpr (WS) {
                br = *(const f32x4*)(b1p + ot*16 + lq*4);
            } else {
                #pragma unroll
                for (int i2 = 0; i2 < 4; ++i2)
                    br[i2] = b1[(ot*16 + lq*4 + i2) * 3];
            }
            U2 lo, hi;
            lo.h[0] = (f16)(acc[0] + br[0]); lo.h[1] = (f16)(acc[1] + br[1]);
            hi.h[0] = (f16)(acc[2] + br[2]); hi.h[1] = (f16)(acc[3] + br[3]);
            qdlo[ot] = lo.i; qdhi[ot] = hi.i;
        }
        // qd -> bq (same 4-lane-group permutation as P relayout)
        #pragma unroll
        for (int hh = 0; hh < 3; ++hh) {
            U8 u;
            #pragma unroll
            for (int w = 0; w < 4; ++w) {
                int idx = (w < 2) ? idxA : idxB;
                int v0 = __shfl((w & 1) ? qdhi[2*hh]     : qdlo[2*hh],     idx);
                int v1 = __shfl((w & 1) ? qdhi[2*hh + 1] : qdlo[2*hh + 1], idx);
                u.i[w] = (lq & 2) ? v1 : v0;
            }
            bq[hh] = u.h;
        }

        // K/V: pt-loop, x double-buffered
        #pragma unroll
        for (int pt = 0; pt < 4; ++pt) {
            float4 (*cur)[2] = (pt & 1) ? xbuf1 : xbuf0;
            float4 (*nxt)[2] = (pt & 1) ? xbuf0 : xbuf1;
            if (pt < 3) {
                #pragma unroll
                for (int ks = 0; ks < 3; ++ks) {
                    nxt[ks][0] = *(const float4*)(xrow[pt+1] + ks * 32 + lq * 8);
                    nxt[ks][1] = *(const float4*)(xrow[pt+1] + ks * 32 + lq * 8 + 4);
                }
            }
            f16x8 xf[3];
            #pragma unroll
            for (int ks = 0; ks < 3; ++ks) xf[ks] = cvt8p(cur[ks][0], cur[ks][1]);
            const int  p   = pt * 16 + lrow;
            const bool pok = (p < 49);
            #pragma unroll
            for (int t = 0; t < 3; ++t) {
                f32x4 acc = {0.f, 0.f, 0.f, 0.f};
                if (kqv[t] == 2) {
                    // V: D[p][c]; lane = channel cc, rows p4..p4+3
                    #pragma unroll
                    for (int ks = 0; ks < 3; ++ks) acc = mfma16(xf[ks], bf[t][ks], acc);
                    float bc;
                    if constexpr (WS) bc = b1p[ob[t] + lrow];
                    else              bc = b1[(ob[t] + lrow - 192)*3 + 2];
                    int cc = cb[t] + lrow;
                    f16x4 pk;
                    #pragma unroll
                    for (int i2 = 0; i2 < 4; ++i2) pk[i2] = (f16)(acc[i2] + bc);
                    int p4 = pt * 16 + lq * 4;
                    if (p4 < 45)       *(f16x4*)(vt_s + cc * VT_STR + p4) = pk;
                    else if (p4 == 48) vt_s[cc * VT_STR + 48] = pk[0];
                } else {
                    // K: D[n'][p]; lane = position p, rows = 4 channels
                    #pragma unroll
                    for (int ks = 0; ks < 3; ++ks) acc = mfma16(bf[t][ks], xf[ks], acc);
                    if (pok) {
                        f32x4 br;
                        if constexpr (WS) {
                            br = *(const f32x4*)(b1p + ob[t] + lq*4);
                        } else {
                            #pragma unroll
                            for (int i2 = 0; i2 < 4; ++i2)
                                br[i2] = b1[(ob[t] + lq*4 + i2 - 96)*3 + 1];
                        }
                        f16x4 pk;
                        #pragma unroll
                        for (int i2 = 0; i2 < 4; ++i2) pk[i2] = (f16)(acc[i2] + br[i2]);
                        *(f16x4*)(k_s + p * QK_STR + cb[t] + lq * 4) = pk;
                    }
                }
            }
        }
    }
    __syncthreads();   // THE barrier: publish k/vt (+pads) to all waves

    const bool mrow = (wh == 7), mcol = (ww == 7);
    const float scale = 0.17677669529663687f;   // 1/sqrt(32)

    // mask values, head-invariant: 0 or -3e38 added via fmaf
    float mv[16];
    {
        const bool am = (m >= 28);
        const bool a4 = (m % 7) >= 4;
        #pragma unroll
        for (int nt = 0; nt < 4; ++nt)
            #pragma unroll
            for (int i2 = 0; i2 < 4; ++i2) {
                int nn = nt * 16 + lq * 4 + i2;
                bool ok = (nn < 49)
                       && (!mrow || (am == (nn >= 28)))
                       && (!mcol || (a4 == ((nn % 7) >= 4)));
                mv[nt*4 + i2] = ok ? 0.f : -3e38f;
            }
    }

    int odlo[6], odhi[6];   // o tiles in registers (consumed by GEMM2)

    // head-pipelined attention: sc holds head hh's S^T; QK(hh+1) runs after
    // PV(hh), its ak loads are issued before softmax(hh).
    f32x4 sc[4];
    #pragma unroll
    for (int nt = 0; nt < 4; ++nt) {
        f16x8 ak = *(const f16x8*)(k_s + (nt*16 + lrow)*QK_STR + lq*8);
        f32x4 z = {0.f, 0.f, 0.f, 0.f};
        sc[nt] = mfma16(ak, bq[0], z);
    }

    #pragma unroll
    for (int hh = 0; hh < 3; ++hh) {
        // issue next head's K-fragment loads (latency hides under softmax)
        f16x8 akn[4];
        if (hh < 2) {
            #pragma unroll
            for (int nt = 0; nt < 4; ++nt)
                akn[nt] = *(const f16x8*)(k_s + (nt*16 + lrow)*QK_STR + (hh+1)*32 + lq*8);
        }
        // V^T loads for this head's PV (also hidden under softmax)
        f16x8 va[2][2];
        #pragma unroll
        for (int et = 0; et < 2; ++et) {
            int vrow = hh * 32 + et * 16 + lrow;
            va[et][0] = *(const f16x8*)(vt_s + vrow * VT_STR + lq * 8);
            va[et][1] = *(const f16x8*)(vt_s + vrow * VT_STR + 32 + lq * 8);
        }
        // no-max softmax: ev = exp(scale*S + mask); masked -> exp(-3e38) = +0.
        float ev[16];
        #pragma unroll
        for (int nt = 0; nt < 4; ++nt)
            #pragma unroll
            for (int i2 = 0; i2 < 4; ++i2)
                ev[nt*4 + i2] = __expf(fmaf(sc[nt][i2], scale, mv[nt*4 + i2]));
        // in-lane partial sum; cross-lane combine deferred past the relayout
        float ts[8];
        #pragma unroll
        for (int k2 = 0; k2 < 8; ++k2) ts[k2] = ev[2*k2] + ev[2*k2+1];
        #pragma unroll
        for (int k2 = 0; k2 < 4; ++k2) ts[k2] += ts[k2+4];
        float sp = (ts[0] + ts[1]) + (ts[2] + ts[3]);

        // pack unnormalized P into dwords: pd[nt][d]
        int pd[4][2];
        #pragma unroll
        for (int nt = 0; nt < 4; ++nt) {
            U2 u0, u1;
            u0.h[0] = (f16)ev[nt*4+0]; u0.h[1] = (f16)ev[nt*4+1];
            u1.h[0] = (f16)ev[nt*4+2]; u1.h[1] = (f16)ev[nt*4+3];
            pd[nt][0] = u0.i; pd[nt][1] = u1.i;
        }
        // relayout S^T regs -> PV B-frags among the 4 lanes sharing m
        U8 ub0, ub1;
        #pragma unroll
        for (int w = 0; w < 4; ++w) {
            int idx = (w < 2) ? idxA : idxB;
            int rr  = w & 1;
            int a0v = __shfl(pd[0][rr], idx);
            int a1v = __shfl(pd[1][rr], idx);
            ub0.i[w] = (lq & 2) ? a1v : a0v;
            int c0v = __shfl(pd[2][rr], idx);
            int c1v = __shfl(pd[3][rr], idx);
            ub1.i[w] = (lq & 2) ? c1v : c0v;
        }
        // sum combine runs concurrently with relayout + PV
        float ssum = sp;
        ssum += __shfl_xor(ssum, 16);
        ssum += __shfl_xor(ssum, 32);
        float inv = 1.0f / ssum;

        // PV swapped: D[e][m]; pack straight to o register tiles
        #pragma unroll
        for (int et = 0; et < 2; ++et) {
            f32x4 z = {0.f, 0.f, 0.f, 0.f};
            f32x4 oc = mfma16(va[et][0], ub0.h, z);
            oc = mfma16(va[et][1], ub1.h, oc);
            U2 lo, hi;
            lo.h[0] = (f16)(oc[0] * inv); lo.h[1] = (f16)(oc[1] * inv);
            hi.h[0] = (f16)(oc[2] * inv); hi.h[1] = (f16)(oc[3] * inv);
            odlo[2*hh + et] = lo.i; odhi[2*hh + et] = hi.i;
        }
        // next head's QK (akn long since arrived)
        if (hh < 2) {
            #pragma unroll
            for (int nt = 0; nt < 4; ++nt) {
                f32x4 z = {0.f, 0.f, 0.f, 0.f};
                sc[nt] = mfma16(akn[nt], bq[hh+1], z);
            }
        }
    }

    // ---- GEMM2 (swapped, 2-stage w2p prefetch): bo from od via shuffles ----
    {
        f16x8 bo[3];
        #pragma unroll
        for (int ks = 0; ks < 3; ++ks) {
            U8 u;
            #pragma unroll
            for (int w = 0; w < 4; ++w) {
                int idx = (w < 2) ? idxA : idxB;
                int v0 = __shfl((w & 1) ? odhi[2*ks]     : odlo[2*ks],     idx);
                int v1 = __shfl((w & 1) ? odhi[2*ks + 1] : odlo[2*ks + 1], idx);
                u.i[w] = (lq & 2) ? v1 : v0;
            }
            bo[ks] = u.h;
        }
        int mm2 = (m < 49) ? m : 48;
        int i = mm2 / 7, j = mm2 - i * 7;
        int orow = wh * 7 + i + 3; if (orow >= 56) orow -= 56;
        int ocol = ww * 7 + j + 3; if (ocol >= 56) ocol -= 56;
        float* op = out + (size_t)(b * 3136 + orow * 56 + ocol) * 96;

        f16x8 aw0[3], aw1[3];
        #pragma unroll
        for (int ks = 0; ks < 3; ++ks) {
            if constexpr (WS)
                aw0[ks] = *(const f16x8*)(w2p + lrow*96 + ks*32 + lq*8);
            else
                aw0[ks] = cvt8(w2 + lrow*96 + ks*32 + lq*8);
        }
        #pragma unroll
        for (int ot2 = 0; ot2 < 6; ++ot2) {
            f16x8* cw = (ot2 & 1) ? aw1 : aw0;
            f16x8* nw = (ot2 & 1) ? aw0 : aw1;
            if (ot2 < 5) {
                #pragma unroll
                for (int ks = 0; ks < 3; ++ks) {
                    if constexpr (WS)
                        nw[ks] = *(const f16x8*)(w2p + ((ot2+1)*16 + lrow)*96 + ks*32 + lq*8);
                    else
                        nw[ks] = cvt8(w2 + ((ot2+1)*16 + lrow)*96 + ks*32 + lq*8);
                }
            }
            f32x4 acc = {0.f, 0.f, 0.f, 0.f};
            #pragma unroll
            for (int ks = 0; ks < 3; ++ks) acc = mfma16(cw[ks], bo[ks], acc);
            f32x4 bias = *(const f32x4*)(b2 + ot2 * 16 + lq * 4);
            if (m < 49) {
                f32x4 o4 = acc + bias;
                *(f32x4*)(op + ot2 * 16 + lq * 4) = o4;
            }
        }
    }
}

// Pre-permute + f16-convert weights into d_ws (runs every launch; graph-safe).
__global__ void prep_weights(const float* __restrict__ w1, const float* __restrict__ b1,
                             const float* __restrict__ w2,
                             f16* __restrict__ w1p, f16* __restrict__ w2p,
                             float* __restrict__ b1p)
{
    int idx = blockIdx.x * 256 + threadIdx.x;
    if (idx < 27648) {                 // w1p[n'][k], n' = kq*96 + c96
        int np = idx / 96, k = idx - np * 96;
        int kq = np / 96, c96 = np - kq * 96;
        w1p[idx] = (f16)w1[(c96 * 3 + kq) * 96 + k];
    } else if (idx < 36864) {
        int i2 = idx - 27648;
        w2p[i2] = (f16)w2[i2];
    } else if (idx < 37152) {
        int np = idx - 36864;
        int kq = np / 96, c96 = np - kq * 96;
        b1p[np] = b1[c96 * 3 + kq];
    }
}

extern "C" void kernel_launch(void* const* d_in, const int* in_sizes, int n_in,
                              void* d_out, int out_size, void* d_ws, size_t ws_size,
                              hipStream_t stream) {
    const float* x  = (const float*)d_in[0];
    const float* w1 = (const float*)d_in[1];
    const float* b1 = (const float*)d_in[2];
    const float* w2 = (const float*)d_in[3];
    const float* b2 = (const float*)d_in[4];
    float* out = (float*)d_out;

    const size_t need = 27648u * 2 + 9216u * 2 + 288u * 4;   // 74,880 B
    if (ws_size >= need) {
        f16*   w1p = (f16*)d_ws;
        f16*   w2p = w1p + 27648;
        float* b1p = (float*)(w2p + 9216);
        prep_weights<<<dim3(146), dim3(256), 0, stream>>>(w1, b1, w2, w1p, w2p, b1p);
        swin_fused<true><<<dim3(4096), dim3(256), 0, stream>>>(
            x, w1, b1, w2, b2, out, w1p, w2p, b1p);
    } else {
        swin_fused<false><<<dim3(4096), dim3(256), 0, stream>>>(
            x, w1, b1, w2, b2, out, nullptr, nullptr, nullptr);
    }
}